// Round 6
// baseline (629.302 us; speedup 1.0000x reference)
//
#include <hip/hip_runtime.h>
#include <math.h>

#define CIN  32
#define COUT 64
#define KVOL 27
#define EPSF 1e-5f

typedef __attribute__((ext_vector_type(8))) short          short8;
typedef __attribute__((ext_vector_type(8))) unsigned short u16x8;
typedef __attribute__((ext_vector_type(4))) float          float4v;

__device__ __forceinline__ float eluf(float x) { return x > 0.f ? x : expm1f(x); }

// f32 -> bf16 round-to-nearest-even
__device__ __forceinline__ unsigned short f2bf(float x) {
    unsigned u = __float_as_uint(x);
    unsigned r = (u + 0x7FFFu + ((u >> 16) & 1u)) >> 16;
    return (unsigned short)r;
}
__device__ __forceinline__ unsigned pk2bf(float lo, float hi) {
    return (unsigned)f2bf(lo) | ((unsigned)f2bf(hi) << 16);
}
__device__ __forceinline__ float bf2f(unsigned short h) {
    return __uint_as_float(((unsigned)h) << 16);
}

// ---------------------------------------------------------------------------
// Weight prep: W1/W2 [k][i][c] f32 -> Wt [k][c][i] bf16 (A^T rows contiguous),
// block 54: Wd [i][c] f32 -> Wdt [c][i] bf16.
// ---------------------------------------------------------------------------
__global__ void cvt_w_kernel(const float* __restrict__ W1, const float* __restrict__ W2,
                             const float* __restrict__ Wd,
                             unsigned short* __restrict__ Wt1, unsigned short* __restrict__ Wt2,
                             unsigned short* __restrict__ Wdt)
{
    int b = blockIdx.x;  // 0..54
    int t = threadIdx.x;
    if (b == 54) {
        for (int e = t; e < CIN * COUT; e += 256) {
            int i = e >> 6, c = e & 63;
            Wdt[c * CIN + i] = f2bf(Wd[e]);
        }
        return;
    }
    const float* W = (b < 27) ? W1 : W2;
    unsigned short* Wt = (b < 27) ? Wt1 : Wt2;
    int k = (b < 27) ? b : b - 27;
    const float* src = W + (size_t)k * (COUT * COUT);
    unsigned short* dst = Wt + (size_t)k * (COUT * COUT);
    for (int e = t; e < COUT * COUT; e += 256) {
        int i = e >> 6, c = e & 63;
        dst[c * COUT + i] = f2bf(src[e]);
    }
}

// ---------------------------------------------------------------------------
// Transposed streaming down-conv: t^T = Wd^T @ feats^T, zero LDS in hot loop.
// Persistent grid + register prefetch. Fused BN0 stats -> red0 (4-way spread).
// ---------------------------------------------------------------------------
__global__ __launch_bounds__(256) void gemm_t_kernel(
    const float* __restrict__ feats, const unsigned short* __restrict__ Wdt,
    int N, unsigned short* __restrict__ t_bf, float* __restrict__ red0)
{
    __shared__ float red_s[64];
    __shared__ float red_q[64];
    int t = threadIdx.x;
    if (t < 64) { red_s[t] = 0.f; red_q[t] = 0.f; }
    __syncthreads();

    int w = t >> 6, lane = t & 63, l15 = lane & 15, quad = lane >> 4;

    // hoist A-frags: aw[mt] = Wd^T rows 16mt+l15, k = quad*8..+7
    short8 aw[4];
    #pragma unroll
    for (int mt = 0; mt < 4; ++mt)
        aw[mt] = *(const short8*)(Wdt + (size_t)(16 * mt + l15) * CIN + quad * 8);

    float s1[16], sq[16];
    #pragma unroll
    for (int e = 0; e < 16; ++e) { s1[e] = 0.f; sq[e] = 0.f; }

    int numTiles = (N + 15) >> 4;
    int stride = gridDim.x * 4;
    int tile = blockIdx.x * 4 + w;

    float4 c0 = make_float4(0.f, 0.f, 0.f, 0.f), c1 = c0;
    {
        int pt = tile * 16 + l15;
        if (tile < numTiles && pt < N) {
            const float4* s = (const float4*)(feats + (size_t)pt * CIN + quad * 8);
            c0 = s[0]; c1 = s[1];
        }
    }

    while (tile < numTiles) {
        int nt = tile + stride;
        float4 n0 = make_float4(0.f, 0.f, 0.f, 0.f), n1 = n0;
        {
            int npt = nt * 16 + l15;
            if (nt < numTiles && npt < N) {
                const float4* s = (const float4*)(feats + (size_t)npt * CIN + quad * 8);
                n0 = s[0]; n1 = s[1];
            }
        }
        union { short8 v; unsigned u[4]; } b;
        b.u[0] = pk2bf(c0.x, c0.y);
        b.u[1] = pk2bf(c0.z, c0.w);
        b.u[2] = pk2bf(c1.x, c1.y);
        b.u[3] = pk2bf(c1.z, c1.w);

        float4v acc[4];
        #pragma unroll
        for (int mt = 0; mt < 4; ++mt)
            acc[mt] = __builtin_amdgcn_mfma_f32_16x16x32_bf16(
                aw[mt], b.v, (float4v){0.f, 0.f, 0.f, 0.f}, 0, 0, 0);

        int pt = tile * 16 + l15;
        if (pt < N) {
            #pragma unroll
            for (int mt = 0; mt < 4; ++mt) {
                uint2 o;
                o.x = pk2bf(acc[mt][0], acc[mt][1]);
                o.y = pk2bf(acc[mt][2], acc[mt][3]);
                *(uint2*)(t_bf + (size_t)pt * COUT + mt * 16 + quad * 4) = o;
            }
        }
        #pragma unroll
        for (int mt = 0; mt < 4; ++mt)
            #pragma unroll
            for (int e = 0; e < 4; ++e) {
                float v = acc[mt][e];
                s1[mt * 4 + e] += v; sq[mt * 4 + e] += v * v;
            }
        c0 = n0; c1 = n1;
        tile = nt;
    }

    #pragma unroll
    for (int m = 1; m <= 8; m <<= 1) {
        #pragma unroll
        for (int e = 0; e < 16; ++e) {
            s1[e] += __shfl_xor(s1[e], m);
            sq[e] += __shfl_xor(sq[e], m);
        }
    }
    if (l15 == 0) {
        #pragma unroll
        for (int e = 0; e < 16; ++e) {
            int ch = (e >> 2) * 16 + quad * 4 + (e & 3);
            atomicAdd(&red_s[ch], s1[e]);
            atomicAdd(&red_q[ch], sq[e]);
        }
    }
    __syncthreads();
    float* dst = red0 + (size_t)(blockIdx.x & 3) * 128;
    if (t < 64)       atomicAdd(&dst[t], red_s[t]);
    else if (t < 128) atomicAdd(&dst[t], red_q[t - 64]);
}

// BN finalize from 4-way-spread sum/sumsq
__global__ void fin_kernel(const float* __restrict__ red, const float* __restrict__ g,
                           const float* __restrict__ b, float* __restrict__ scale,
                           float* __restrict__ shift, int cnt)
{
    int c = threadIdx.x;  // 64
    float s = 0.f, q = 0.f;
    #pragma unroll
    for (int i = 0; i < 4; ++i) { s += red[i * 128 + c]; q += red[i * 128 + 64 + c]; }
    float m = s / (float)cnt;
    float var = q / (float)cnt - m * m;
    float sc = g[c] / sqrtf(var + EPSF);
    scale[c] = sc;
    shift[c] = b[c] - m * sc;
}

// ---------------------------------------------------------------------------
// Bucket build: pooling cell = 2x2x4 = 16 voxels max -> fixed capacity 16.
// ---------------------------------------------------------------------------
__global__ void bucket_kernel(const int* __restrict__ pool_seg,
                              int* __restrict__ cnt, int* __restrict__ bucket, int N)
{
    int j = blockIdx.x * 256 + threadIdx.x;
    if (j < N) {
        int s = pool_seg[j];
        int pos = atomicAdd(&cnt[s], 1);
        bucket[(size_t)s * 16 + pos] = j;
    }
}

// ---------------------------------------------------------------------------
// Gather-only pool: thread = (segment, 4 channels). max/min over raw t rows,
// then BN0+ELU on the pooled value (monotone per channel; min covers sc<0).
// ---------------------------------------------------------------------------
__global__ __launch_bounds__(256) void pool_max_kernel(
    const unsigned short* __restrict__ t_bf,
    const int* __restrict__ cnt, const int* __restrict__ bucket,
    const float* __restrict__ scale0, const float* __restrict__ shift0,
    unsigned short* __restrict__ down_bf, int M)
{
    int id = blockIdx.x * 256 + threadIdx.x;
    int s = id >> 4, cg = id & 15;
    if (s >= M) return;
    int n = cnt[s];
    const int4* bk4 = (const int4*)(bucket + (size_t)s * 16);
    float4 mx = make_float4(-INFINITY, -INFINITY, -INFINITY, -INFINITY);
    float4 mn = make_float4( INFINITY,  INFINITY,  INFINITY,  INFINITY);
    #pragma unroll
    for (int ch = 0; ch < 4; ++ch) {
        if (ch * 4 >= n) break;
        int4 b4 = bk4[ch];
        #pragma unroll
        for (int e = 0; e < 4; ++e) {
            int p = ch * 4 + e;
            if (p < n) {
                int idx = (e == 0) ? b4.x : (e == 1) ? b4.y : (e == 2) ? b4.z : b4.w;
                ushort4 v = *(const ushort4*)(t_bf + (size_t)idx * COUT + cg * 4);
                float f0 = bf2f(v.x), f1 = bf2f(v.y), f2 = bf2f(v.z), f3 = bf2f(v.w);
                mx.x = fmaxf(mx.x, f0); mn.x = fminf(mn.x, f0);
                mx.y = fmaxf(mx.y, f1); mn.y = fminf(mn.y, f1);
                mx.z = fmaxf(mx.z, f2); mn.z = fminf(mn.z, f2);
                mx.w = fmaxf(mx.w, f3); mn.w = fminf(mn.w, f3);
            }
        }
    }
    int c0 = cg * 4;
    float4 sc = *(const float4*)(scale0 + c0);
    float4 sh = *(const float4*)(shift0 + c0);
    ushort4 o;
    o.x = f2bf(eluf(sc.x * (sc.x >= 0.f ? mx.x : mn.x) + sh.x));
    o.y = f2bf(eluf(sc.y * (sc.y >= 0.f ? mx.y : mn.y) + sh.y));
    o.z = f2bf(eluf(sc.z * (sc.z >= 0.f ? mx.z : mn.z) + sh.z));
    o.w = f2bf(eluf(sc.w * (sc.w >= 0.f ? mx.w : mn.w) + sh.w));
    *(ushort4*)(down_bf + (size_t)s * COUT + c0) = o;
}

// invert (k, pairlist) maps into nbr[j][28] (row-major, int4-aligned rows)
__global__ void nbr_kernel(const int* __restrict__ conv_out, const int* __restrict__ conv_in,
                           int* __restrict__ nbr, int L, int M)
{
    int k = blockIdx.y;
    int idx = blockIdx.x * 256 + threadIdx.x;
    if (idx < L) {
        int e = k * L + idx;
        int j = conv_out[e];
        if (j < M) nbr[(size_t)j * 28 + k] = conv_in[e];
    }
}

// o1t = bf16( ELU(scale1*o1_bf + shift1) )  -- conv2's input
__global__ void bn_elu_cvt_kernel(const unsigned short* __restrict__ in,
                                  const float* __restrict__ scale,
                                  const float* __restrict__ shift,
                                  unsigned short* __restrict__ out, int n4)
{
    int i = blockIdx.x * 256 + threadIdx.x;
    if (i < n4) {
        int c0 = (i * 4) & 63;
        ushort4 v = ((const ushort4*)in)[i];
        float4 sc = *(const float4*)(scale + c0);
        float4 sh = *(const float4*)(shift + c0);
        ushort4 o;
        o.x = f2bf(eluf(bf2f(v.x) * sc.x + sh.x));
        o.y = f2bf(eluf(bf2f(v.y) * sc.y + sh.y));
        o.z = f2bf(eluf(bf2f(v.z) * sc.z + sh.z));
        o.w = f2bf(eluf(bf2f(v.w) * sc.w + sh.w));
        ((ushort4*)out)[i] = o;
    }
}

// ---------------------------------------------------------------------------
// Transposed MFMA sparse conv: out^T = sum_k Wt[k] @ in^T.
// Wave = 16 points x 64 channels; B-operand gathered global->reg (16 B/lane),
// A-operand = Wt[k] from double-buffered LDS (stride 72: 2-way = free).
// All 27 nbr indices register-resident; B(k+1) prefetch overlaps MFMA(k).
// One barrier per k (W dbuf swap). Raw bf16 packed output + exact f32 stats.
// ---------------------------------------------------------------------------
__global__ __launch_bounds__(256) void conv_mfma_kernel(
    const unsigned short* __restrict__ in, const unsigned short* __restrict__ Wt,
    const int* __restrict__ nbr, int M,
    unsigned short* __restrict__ out_bf, float* __restrict__ red)
{
    __shared__ __align__(16) unsigned short W_lds[2][64 * 72];  // 18.4 KB
    __shared__ float red_s[64];
    __shared__ float red_q[64];
    int t = threadIdx.x;
    int w = t >> 6, lane = t & 63, l15 = lane & 15, quad = lane >> 4;
    if (t < 64) { red_s[t] = 0.f; red_q[t] = 0.f; }

    int pt = blockIdx.x * 64 + w * 16 + l15;

    // all 27 neighbor indices -> registers (7 x int4 from padded row of 28)
    int idx[28];
    if (pt < M) {
        const int4* src = (const int4*)(nbr + (size_t)pt * 28);
        #pragma unroll
        for (int q = 0; q < 7; ++q) {
            int4 v = src[q];
            idx[q * 4 + 0] = v.x; idx[q * 4 + 1] = v.y;
            idx[q * 4 + 2] = v.z; idx[q * 4 + 3] = v.w;
        }
    } else {
        #pragma unroll
        for (int e = 0; e < 28; ++e) idx[e] = -1;
    }

    int wc = t >> 2, wq = t & 3;  // W staging: row, 32B-chunk
    {   // stage W[0] -> buf 0
        const u16x8* src = (const u16x8*)(Wt + wc * COUT + 16 * wq);
        u16x8* dst = (u16x8*)(&W_lds[0][wc * 72 + 16 * wq]);
        dst[0] = src[0]; dst[1] = src[1];
    }

    float4v acc[4];
    #pragma unroll
    for (int mt = 0; mt < 4; ++mt) acc[mt] = (float4v){0.f, 0.f, 0.f, 0.f};

    // prefetch B for k=0
    short8 b0c = {0,0,0,0,0,0,0,0}, b1c = b0c;
    {
        int ix = idx[0];
        if (ix >= 0) {
            b0c = *(const short8*)(in + (size_t)ix * COUT + quad * 8);
            b1c = *(const short8*)(in + (size_t)ix * COUT + 32 + quad * 8);
        }
    }
    __syncthreads();  // W[0] staged

    for (int k = 0; k < KVOL; ++k) {
        // stage W[k+1] into the other buffer (read next iteration)
        if (k + 1 < KVOL) {
            const u16x8* src = (const u16x8*)(Wt + (size_t)(k + 1) * (COUT * COUT)
                                              + wc * COUT + 16 * wq);
            u16x8* dst = (u16x8*)(&W_lds[(k + 1) & 1][wc * 72 + 16 * wq]);
            dst[0] = src[0]; dst[1] = src[1];
        }
        // prefetch B for k+1 (indices register-resident -> issues immediately)
        short8 b0n = {0,0,0,0,0,0,0,0}, b1n = b0n;
        if (k + 1 < KVOL) {
            int ix = idx[k + 1];
            if (ix >= 0) {
                b0n = *(const short8*)(in + (size_t)ix * COUT + quad * 8);
                b1n = *(const short8*)(in + (size_t)ix * COUT + 32 + quad * 8);
            }
        }
        // MFMA on current B with W[k] from LDS
        const unsigned short* wl = W_lds[k & 1];
        #pragma unroll
        for (int mt = 0; mt < 4; ++mt) {
            short8 a0 = *(const short8*)(wl + (16 * mt + l15) * 72 + quad * 8);
            short8 a1 = *(const short8*)(wl + (16 * mt + l15) * 72 + 32 + quad * 8);
            acc[mt] = __builtin_amdgcn_mfma_f32_16x16x32_bf16(a0, b0c, acc[mt], 0, 0, 0);
            acc[mt] = __builtin_amdgcn_mfma_f32_16x16x32_bf16(a1, b1c, acc[mt], 0, 0, 0);
        }
        b0c = b0n; b1c = b1n;
        __syncthreads();  // W[k+1] staged; W_lds[k&1] free for k+2
    }

    // packed bf16 stores: lane holds channels mt*16+quad*4+e of point pt
    if (pt < M) {
        #pragma unroll
        for (int mt = 0; mt < 4; ++mt) {
            uint2 o;
            o.x = pk2bf(acc[mt][0], acc[mt][1]);
            o.y = pk2bf(acc[mt][2], acc[mt][3]);
            *(uint2*)(out_bf + (size_t)pt * COUT + mt * 16 + quad * 4) = o;
        }
    }
    // fused BN stats from exact f32 accs (pts >= M contribute zeros)
    float s1[16], sq[16];
    #pragma unroll
    for (int mt = 0; mt < 4; ++mt)
        #pragma unroll
        for (int e = 0; e < 4; ++e) {
            float v = acc[mt][e];
            s1[mt * 4 + e] = v; sq[mt * 4 + e] = v * v;
        }
    #pragma unroll
    for (int m = 1; m <= 8; m <<= 1) {
        #pragma unroll
        for (int e = 0; e < 16; ++e) {
            s1[e] += __shfl_xor(s1[e], m);
            sq[e] += __shfl_xor(sq[e], m);
        }
    }
    if (l15 == 0) {
        #pragma unroll
        for (int e = 0; e < 16; ++e) {
            int ch = (e >> 2) * 16 + quad * 4 + (e & 3);
            atomicAdd(&red_s[ch], s1[e]);
            atomicAdd(&red_q[ch], sq[e]);
        }
    }
    __syncthreads();
    float* dst = red + (size_t)(blockIdx.x & 3) * 128;
    if (t < 64)       atomicAdd(&dst[t], red_s[t]);
    else if (t < 128) atomicAdd(&dst[t], red_q[t - 64]);
}

// out = elu( elu(scale2*raw + shift2) + down ), raw/down packed bf16
__global__ void final_kernel(const unsigned short* __restrict__ raw,
                             const unsigned short* __restrict__ down_bf,
                             const float* __restrict__ scale2, const float* __restrict__ shift2,
                             float* __restrict__ out, int n4)
{
    int i = blockIdx.x * 256 + threadIdx.x;
    if (i < n4) {
        int c0 = (i * 4) & 63;
        ushort4 r = ((const ushort4*)raw)[i];
        ushort4 d = ((const ushort4*)down_bf)[i];
        float4 sc = *(const float4*)(scale2 + c0);
        float4 sh = *(const float4*)(shift2 + c0);
        float4 o;
        o.x = eluf(eluf(bf2f(r.x) * sc.x + sh.x) + bf2f(d.x));
        o.y = eluf(eluf(bf2f(r.y) * sc.y + sh.y) + bf2f(d.y));
        o.z = eluf(eluf(bf2f(r.z) * sc.z + sh.z) + bf2f(d.z));
        o.w = eluf(eluf(bf2f(r.w) * sc.w + sh.w) + bf2f(d.w));
        ((float4*)out)[i] = o;
    }
}

extern "C" void kernel_launch(void* const* d_in, const int* in_sizes, int n_in,
                              void* d_out, int out_size, void* d_ws, size_t ws_size,
                              hipStream_t stream)
{
    (void)n_in; (void)ws_size;
    const float* feats    = (const float*)d_in[0];
    const float* Wd       = (const float*)d_in[1];
    const float* g0       = (const float*)d_in[2];
    const float* b0       = (const float*)d_in[3];
    const float* W1       = (const float*)d_in[4];
    const float* g1       = (const float*)d_in[5];
    const float* b1       = (const float*)d_in[6];
    const float* W2       = (const float*)d_in[7];
    const float* g2       = (const float*)d_in[8];
    const float* b2       = (const float*)d_in[9];
    const int*   pool_seg = (const int*)d_in[10];
    const int*   conv_in  = (const int*)d_in[11];
    const int*   conv_out = (const int*)d_in[12];

    int N = in_sizes[0] / CIN;
    int M = out_size / COUT;
    int L = in_sizes[11] / KVOL;

    char* ws = (char*)d_ws;
    size_t off = 0;
    auto alloc = [&](size_t bytes) -> void* {
        void* p = ws + off;
        off = (off + bytes + 255) & ~(size_t)255;
        return p;
    };
    unsigned short* down_bf = (unsigned short*)alloc((size_t)M * COUT * 2);
    unsigned short* o1_bf   = (unsigned short*)alloc((size_t)M * COUT * 2);
    unsigned short* o1t     = (unsigned short*)alloc((size_t)M * COUT * 2);
    unsigned short* o2_bf   = (unsigned short*)alloc((size_t)M * COUT * 2);
    unsigned short* t_bf    = (unsigned short*)alloc((size_t)N * COUT * 2);
    int*            nbr     = (int*)alloc((size_t)M * 28 * 4);
    unsigned short* Wt1     = (unsigned short*)alloc((size_t)KVOL * COUT * COUT * 2);
    unsigned short* Wt2     = (unsigned short*)alloc((size_t)KVOL * COUT * COUT * 2);
    unsigned short* Wdt     = (unsigned short*)alloc((size_t)CIN * COUT * 2);
    int*            cnt     = (int*)alloc((size_t)M * 4);
    int*            bucket  = (int*)alloc((size_t)M * 16 * 4);
    float* red  = (float*)alloc((size_t)1536 * 4);
    float* red0 = red, *red1 = red + 512, *red2 = red + 1024;
    float* sreg = (float*)alloc((size_t)6 * 64 * 4);
    float* scale0 = sreg, *shift0 = sreg + 64;
    float* scale1 = sreg + 128, *shift1 = sreg + 192;
    float* scale2 = sreg + 256, *shift2 = sreg + 320;

    hipMemsetAsync(nbr, 0xFF, (size_t)M * 28 * 4, stream);  // -1 = missing neighbor
    hipMemsetAsync(cnt, 0, (size_t)M * 4, stream);          // bucket counters
    hipMemsetAsync(red, 0, (size_t)1536 * 4, stream);       // stat accumulators

    cvt_w_kernel<<<55, 256, 0, stream>>>(W1, W2, Wd, Wt1, Wt2, Wdt);
    gemm_t_kernel<<<1024, 256, 0, stream>>>(feats, Wdt, N, t_bf, red0);
    fin_kernel<<<1, 64, 0, stream>>>(red0, g0, b0, scale0, shift0, N);
    bucket_kernel<<<(N + 255) / 256, 256, 0, stream>>>(pool_seg, cnt, bucket, N);
    pool_max_kernel<<<(M * 16 + 255) / 256, 256, 0, stream>>>(
        t_bf, cnt, bucket, scale0, shift0, down_bf, M);
    dim3 gn((L + 255) / 256, KVOL);
    nbr_kernel<<<gn, 256, 0, stream>>>(conv_out, conv_in, nbr, L, M);

    int cblocks = (M + 63) / 64;
    int n4 = M * COUT / 4;
    conv_mfma_kernel<<<cblocks, 256, 0, stream>>>(down_bf, Wt1, nbr, M, o1_bf, red1);
    fin_kernel<<<1, 64, 0, stream>>>(red1, g1, b1, scale1, shift1, M);
    bn_elu_cvt_kernel<<<(n4 + 255) / 256, 256, 0, stream>>>(o1_bf, scale1, shift1, o1t, n4);
    conv_mfma_kernel<<<cblocks, 256, 0, stream>>>(o1t, Wt2, nbr, M, o2_bf, red2);
    fin_kernel<<<1, 64, 0, stream>>>(red2, g2, b2, scale2, shift2, M);
    final_kernel<<<(n4 + 255) / 256, 256, 0, stream>>>(
        o2_bf, down_bf, scale2, shift2, (float*)d_out, n4);
}